// Round 5
// baseline (97.537 us; speedup 1.0000x reference)
//
#include <hip/hip_runtime.h>

// CrossNet fused, R5: R1 structure (block-per-row, 256 thr) with minimized
// per-thread register state to reach 8 waves/SIMD occupancy:
//  - t1 = b0.w1, t2 = (b0+b1).w2 are row-independent -> tiny pre-kernel.
//  - main loop reads only 4 streams (x, w0, w1, w2); keeps only xv[4] cached.
//  - epilogue re-reads b (48 KB, L2-resident) and rebuilds cumsums on the fly.
// History: R1 45.9us (best); R2 nontemporal 70.7 (BAD); R3 two-phase 60.9
// (BAD); R4 wave-per-row fat regs 53.9 (BAD).

constexpr int BLK = 256;

typedef float f32x4 __attribute__((ext_vector_type(4)));

__device__ __forceinline__ float dot4(f32x4 a, f32x4 b) {
    return a.x * b.x + a.y * b.y + a.z * b.z + a.w * b.w;
}

// ---- tiny pre-kernel: t1 = b0.w1, t2 = (b0+b1).w2 (one block) -------------
__global__ __launch_bounds__(BLK) void crossnet_consts(
    const float* __restrict__ w,
    const float* __restrict__ b,
    float* __restrict__ ts,   // ts[0]=t1, ts[1]=t2
    int N)
{
    const int tid = threadIdx.x;
    const f32x4* w1 = (const f32x4*)(w + N);
    const f32x4* w2 = (const f32x4*)(w + 2 * (size_t)N);
    const f32x4* b0 = (const f32x4*)(b);
    const f32x4* b1 = (const f32x4*)(b + N);

    float q1 = 0.f, q2 = 0.f;
    const int nchunk = N / 4;
    for (int idx = tid; idx < nchunk; idx += BLK) {
        const f32x4 ba = b0[idx];
        const f32x4 bb = b1[idx];
        q1 += dot4(ba, w1[idx]);
        q2 += dot4(ba + bb, w2[idx]);
    }
    #pragma unroll
    for (int off = 32; off > 0; off >>= 1) {
        q1 += __shfl_down(q1, off);
        q2 += __shfl_down(q2, off);
    }
    __shared__ float red[4][2];
    const int wave = tid >> 6, lane = tid & 63;
    if (lane == 0) { red[wave][0] = q1; red[wave][1] = q2; }
    __syncthreads();
    if (tid == 0) {
        ts[0] = red[0][0] + red[1][0] + red[2][0] + red[3][0];
        ts[1] = red[0][1] + red[1][1] + red[2][1] + red[3][1];
    }
}

// ---- main fused kernel -----------------------------------------------------
__global__ __launch_bounds__(BLK, 8) void crossnet_fused(
    const float* __restrict__ x,
    const float* __restrict__ w,
    const float* __restrict__ b,
    const float* __restrict__ ts,
    float* __restrict__ out,
    int B, int N)
{
    const int row = blockIdx.x;
    const int tid = threadIdx.x;

    const size_t base = (size_t)row * N;
    const f32x4* x4 = (const f32x4*)(x + base);
    const f32x4* w0 = (const f32x4*)(w);
    const f32x4* w1 = (const f32x4*)(w + N);
    const f32x4* w2 = (const f32x4*)(w + 2 * (size_t)N);

    f32x4 xv[4];
    float p0 = 0.f, p1 = 0.f, p2 = 0.f;

    #pragma unroll
    for (int c = 0; c < 4; ++c) {
        const int idx = c * BLK + tid;
        const f32x4 xx = x4[idx];
        xv[c] = xx;
        p0 += dot4(xx, w0[idx]);
        p1 += dot4(xx, w1[idx]);
        p2 += dot4(xx, w2[idx]);
    }

    #pragma unroll
    for (int off = 32; off > 0; off >>= 1) {
        p0 += __shfl_down(p0, off);
        p1 += __shfl_down(p1, off);
        p2 += __shfl_down(p2, off);
    }

    __shared__ float red[4][4];
    const int wave = tid >> 6, lane = tid & 63;
    if (lane == 0) {
        red[wave][0] = p0; red[wave][1] = p1; red[wave][2] = p2;
    }
    __syncthreads();

    const float u0 = red[0][0] + red[1][0] + red[2][0] + red[3][0];
    const float u1 = red[0][1] + red[1][1] + red[2][1] + red[3][1];
    const float u2 = red[0][2] + red[1][2] + red[2][2] + red[3][2];
    const float t1 = ts[0];
    const float t2 = ts[1];

    const float c1 = 1.0f + u0;          // x1 = x*c1 + b0
    const float s1 = c1 * u1 + t1;
    const float c2 = c1 + s1;            // x2 = x*c2 + b0+b1
    const float s2 = c2 * u2 + t2;
    const float c3 = c2 + s2;            // x3 = x*c3 + b0+b1+b2

    const f32x4* b0p = (const f32x4*)(b);
    const f32x4* b1p = (const f32x4*)(b + N);
    const f32x4* b2p = (const f32x4*)(b + 2 * (size_t)N);

    f32x4* o0 = (f32x4*)(out + base);
    f32x4* o1 = (f32x4*)(out + (size_t)B * N + base);
    f32x4* o2 = (f32x4*)(out + 2 * (size_t)B * N + base);

    #pragma unroll
    for (int c = 0; c < 4; ++c) {
        const int idx = c * BLK + tid;
        const f32x4 ba = b0p[idx];       // L2-hit (48 KB shared by all blocks)
        const f32x4 bb = b1p[idx];
        const f32x4 bc = b2p[idx];
        const f32x4 cb2 = ba + bb;
        const f32x4 cb3 = cb2 + bc;
        o0[idx] = xv[c] * c1 + ba;
        o1[idx] = xv[c] * c2 + cb2;
        o2[idx] = xv[c] * c3 + cb3;
    }
}

extern "C" void kernel_launch(void* const* d_in, const int* in_sizes, int n_in,
                              void* d_out, int out_size, void* d_ws, size_t ws_size,
                              hipStream_t stream) {
    const float* x = (const float*)d_in[0];
    const float* w = (const float*)d_in[1];
    const float* b = (const float*)d_in[2];
    float* out = (float*)d_out;
    float* ts = (float*)d_ws;

    const int N = in_sizes[1] / 3;   // w is [3, N, 1]
    const int B = in_sizes[0] / N;   // x is [B, N]

    crossnet_consts<<<1, BLK, 0, stream>>>(w, b, ts, N);
    crossnet_fused<<<B, BLK, 0, stream>>>(x, w, b, ts, out, B, N);
}

// Round 6
// 50.911 us; speedup vs baseline: 1.9158x; 1.9158x over previous
//
#include <hip/hip_runtime.h>

// CrossNet fused R6: R1 structure (block-per-row, 256 thr, single dispatch)
// minus the 48-VGPR cumulative-b register cache. b is re-read in the epilogue
// (48 KB, L2-resident broadcast) so per-thread live state across the barrier
// is just xv[4] (16 VGPR) -> higher natural occupancy, no forced bounds.
// History: R1 45.9us (best); R2 nontemporal 70.7; R3 two-phase 60.9;
// R4 wave-per-row 53.9; R5 forced launch_bounds(,8)+pre-kernel 97.5 (spills).

constexpr int BLK = 256;

typedef float f32x4 __attribute__((ext_vector_type(4)));

__device__ __forceinline__ float dot4(f32x4 a, f32x4 b) {
    return a.x * b.x + a.y * b.y + a.z * b.z + a.w * b.w;
}

__global__ __launch_bounds__(BLK) void crossnet_fused(
    const float* __restrict__ x,
    const float* __restrict__ w,
    const float* __restrict__ b,
    float* __restrict__ out,
    int B, int N)
{
    const int row = blockIdx.x;
    const int tid = threadIdx.x;

    const size_t base = (size_t)row * N;
    const f32x4* x4 = (const f32x4*)(x + base);
    const f32x4* w0 = (const f32x4*)(w);
    const f32x4* w1 = (const f32x4*)(w + N);
    const f32x4* w2 = (const f32x4*)(w + 2 * (size_t)N);
    const f32x4* b0 = (const f32x4*)(b);
    const f32x4* b1 = (const f32x4*)(b + N);
    const f32x4* b2 = (const f32x4*)(b + 2 * (size_t)N);

    f32x4 xv[4];                         // only x stays in registers
    float p0 = 0.f, p1 = 0.f, p2 = 0.f;  // x . w0/w1/w2
    float q1 = 0.f, q2 = 0.f;            // b0 . w1, (b0+b1) . w2

    #pragma unroll
    for (int c = 0; c < 4; ++c) {
        const int idx = c * BLK + tid;
        const f32x4 xx = x4[idx];
        const f32x4 wa = w0[idx];
        const f32x4 wb = w1[idx];
        const f32x4 wc = w2[idx];
        const f32x4 ba = b0[idx];
        const f32x4 bb = b1[idx];
        xv[c] = xx;
        p0 += dot4(xx, wa);
        p1 += dot4(xx, wb);
        p2 += dot4(xx, wc);
        q1 += dot4(ba, wb);
        q2 += dot4(ba + bb, wc);
    }

    #pragma unroll
    for (int off = 32; off > 0; off >>= 1) {
        p0 += __shfl_down(p0, off);
        p1 += __shfl_down(p1, off);
        p2 += __shfl_down(p2, off);
        q1 += __shfl_down(q1, off);
        q2 += __shfl_down(q2, off);
    }

    __shared__ float red[4][8];
    const int wave = tid >> 6, lane = tid & 63;
    if (lane == 0) {
        red[wave][0] = p0; red[wave][1] = p1; red[wave][2] = p2;
        red[wave][3] = q1; red[wave][4] = q2;
    }
    __syncthreads();

    const float u0 = red[0][0] + red[1][0] + red[2][0] + red[3][0];
    const float u1 = red[0][1] + red[1][1] + red[2][1] + red[3][1];
    const float u2 = red[0][2] + red[1][2] + red[2][2] + red[3][2];
    const float t1 = red[0][3] + red[1][3] + red[2][3] + red[3][3];
    const float t2 = red[0][4] + red[1][4] + red[2][4] + red[3][4];

    const float c1 = 1.0f + u0;          // x1 = x*c1 + b0
    const float s1 = c1 * u1 + t1;
    const float c2 = c1 + s1;            // x2 = x*c2 + b0+b1
    const float s2 = c2 * u2 + t2;
    const float c3 = c2 + s2;            // x3 = x*c3 + b0+b1+b2

    f32x4* o0 = (f32x4*)(out + base);
    f32x4* o1 = (f32x4*)(out + (size_t)B * N + base);
    f32x4* o2 = (f32x4*)(out + 2 * (size_t)B * N + base);

    #pragma unroll
    for (int c = 0; c < 4; ++c) {
        const int idx = c * BLK + tid;
        const f32x4 ba = b0[idx];        // L2-hit re-read (48 KB total)
        const f32x4 bb = b1[idx];
        const f32x4 bc = b2[idx];
        const f32x4 cb2 = ba + bb;
        const f32x4 cb3 = cb2 + bc;
        o0[idx] = xv[c] * c1 + ba;
        o1[idx] = xv[c] * c2 + cb2;
        o2[idx] = xv[c] * c3 + cb3;
    }
}

extern "C" void kernel_launch(void* const* d_in, const int* in_sizes, int n_in,
                              void* d_out, int out_size, void* d_ws, size_t ws_size,
                              hipStream_t stream) {
    const float* x = (const float*)d_in[0];
    const float* w = (const float*)d_in[1];
    const float* b = (const float*)d_in[2];
    float* out = (float*)d_out;

    const int N = in_sizes[1] / 3;   // w is [3, N, 1]
    const int B = in_sizes[0] / N;   // x is [B, N]

    crossnet_fused<<<B, BLK, 0, stream>>>(x, w, b, out, B, N);
}

// Round 7
// 47.737 us; speedup vs baseline: 2.0432x; 1.0665x over previous
//
#include <hip/hip_runtime.h>

// CrossNet fused R7: persistent blocks, register-resident weights.
//   x_k = x*c_k + cumsum(b)_k ; c_k per-row scalars from 3 dots + 2 consts.
// 512 blocks x 8 rows, BLK=512 (2 f32x4/thread/row).
// w0..w2 + cumsum-b live in registers for the whole block (loaded once);
// q1,q2 block-reduced once. Per row: load x only, dots vs register w,
// one-barrier LDS reduce, prefetch next x, pure store burst (no loads).
// History: R1 45.9us (best); R2 nt 70.7; R3 split 60.9; R4 wave-row 53.9;
// R5 forced lb(,8) 97.5 (spills); R6 b-reread epilogue 50.9.

constexpr int BLK = 512;
constexpr int CHUNK = 2;   // f32x4 per thread per row (N/4/BLK = 2 for N=4096)

typedef float f32x4 __attribute__((ext_vector_type(4)));

__device__ __forceinline__ float dot4(f32x4 a, f32x4 b) {
    return a.x * b.x + a.y * b.y + a.z * b.z + a.w * b.w;
}

__global__ __launch_bounds__(BLK) void crossnet_persist(
    const float* __restrict__ x,
    const float* __restrict__ w,
    const float* __restrict__ b,
    float* __restrict__ out,
    int B, int N, int rows_per_blk)
{
    const int tid = threadIdx.x;
    const int wave = tid >> 6;
    const int lane = tid & 63;
    const int nwaves = BLK / 64;

    const f32x4* w0 = (const f32x4*)(w);
    const f32x4* w1 = (const f32x4*)(w + N);
    const f32x4* w2 = (const f32x4*)(w + 2 * (size_t)N);
    const f32x4* b0 = (const f32x4*)(b);
    const f32x4* b1 = (const f32x4*)(b + N);
    const f32x4* b2 = (const f32x4*)(b + 2 * (size_t)N);

    // ---- one-time preload: w and cumsum-b into registers ----
    f32x4 wv0[CHUNK], wv1[CHUNK], wv2[CHUNK];
    f32x4 cb1[CHUNK], cb2[CHUNK], cb3[CHUNK];
    float q1 = 0.f, q2 = 0.f;   // b0.w1, (b0+b1).w2

    #pragma unroll
    for (int c = 0; c < CHUNK; ++c) {
        const int idx = c * BLK + tid;
        wv0[c] = w0[idx];
        wv1[c] = w1[idx];
        wv2[c] = w2[idx];
        const f32x4 ba = b0[idx];
        const f32x4 bb = b1[idx];
        const f32x4 bc = b2[idx];
        cb1[c] = ba;
        cb2[c] = ba + bb;
        cb3[c] = cb2[c] + bc;
        q1 += dot4(ba, wv1[c]);
        q2 += dot4(cb2[c], wv2[c]);
    }

    __shared__ float redq[BLK / 64][2];
    __shared__ float red[2][BLK / 64][3];   // double-buffered per-row slots

    #pragma unroll
    for (int off = 32; off > 0; off >>= 1) {
        q1 += __shfl_down(q1, off);
        q2 += __shfl_down(q2, off);
    }
    if (lane == 0) { redq[wave][0] = q1; redq[wave][1] = q2; }
    __syncthreads();
    float t1 = 0.f, t2 = 0.f;
    #pragma unroll
    for (int wv = 0; wv < nwaves; ++wv) { t1 += redq[wv][0]; t2 += redq[wv][1]; }

    // ---- row loop ----
    const int row0 = blockIdx.x * rows_per_blk;

    f32x4 xcur[CHUNK];
    {
        const f32x4* x4 = (const f32x4*)(x + (size_t)row0 * N);
        #pragma unroll
        for (int c = 0; c < CHUNK; ++c) xcur[c] = x4[c * BLK + tid];
    }

    for (int r = 0; r < rows_per_blk; ++r) {
        const size_t base = (size_t)(row0 + r) * N;

        // dots against register-resident w
        float p0 = 0.f, p1 = 0.f, p2 = 0.f;
        #pragma unroll
        for (int c = 0; c < CHUNK; ++c) {
            p0 += dot4(xcur[c], wv0[c]);
            p1 += dot4(xcur[c], wv1[c]);
            p2 += dot4(xcur[c], wv2[c]);
        }
        #pragma unroll
        for (int off = 32; off > 0; off >>= 1) {
            p0 += __shfl_down(p0, off);
            p1 += __shfl_down(p1, off);
            p2 += __shfl_down(p2, off);
        }
        const int buf = r & 1;
        if (lane == 0) {
            red[buf][wave][0] = p0; red[buf][wave][1] = p1; red[buf][wave][2] = p2;
        }
        __syncthreads();
        float u0 = 0.f, u1 = 0.f, u2 = 0.f;
        #pragma unroll
        for (int wv = 0; wv < nwaves; ++wv) {
            u0 += red[buf][wv][0]; u1 += red[buf][wv][1]; u2 += red[buf][wv][2];
        }

        const float c1 = 1.0f + u0;          // x1 = x*c1 + b0
        const float s1 = c1 * u1 + t1;
        const float c2 = c1 + s1;            // x2 = x*c2 + b0+b1
        const float s2 = c2 * u2 + t2;
        const float c3 = c2 + s2;            // x3 = x*c3 + b0+b1+b2

        // prefetch next row's x (overlaps the store burst below)
        f32x4 xnext[CHUNK];
        if (r + 1 < rows_per_blk) {
            const f32x4* xn = (const f32x4*)(x + base + N);
            #pragma unroll
            for (int c = 0; c < CHUNK; ++c) xnext[c] = xn[c * BLK + tid];
        }

        // pure store burst from registers
        f32x4* o0 = (f32x4*)(out + base);
        f32x4* o1 = (f32x4*)(out + (size_t)B * N + base);
        f32x4* o2 = (f32x4*)(out + 2 * (size_t)B * N + base);
        #pragma unroll
        for (int c = 0; c < CHUNK; ++c) {
            const int idx = c * BLK + tid;
            o0[idx] = xcur[c] * c1 + cb1[c];
            o1[idx] = xcur[c] * c2 + cb2[c];
            o2[idx] = xcur[c] * c3 + cb3[c];
        }

        #pragma unroll
        for (int c = 0; c < CHUNK; ++c) xcur[c] = xnext[c];
    }
}

extern "C" void kernel_launch(void* const* d_in, const int* in_sizes, int n_in,
                              void* d_out, int out_size, void* d_ws, size_t ws_size,
                              hipStream_t stream) {
    const float* x = (const float*)d_in[0];
    const float* w = (const float*)d_in[1];
    const float* b = (const float*)d_in[2];
    float* out = (float*)d_out;

    const int N = in_sizes[1] / 3;   // w is [3, N, 1]
    const int B = in_sizes[0] / N;   // x is [B, N]

    const int nblocks = 512;         // 2 blocks/CU target
    const int rows_per_blk = B / nblocks;   // 8 for B=4096

    crossnet_persist<<<nblocks, BLK, 0, stream>>>(x, w, b, out, B, N, rows_per_blk);
}

// Round 8
// 45.877 us; speedup vs baseline: 2.1260x; 1.0405x over previous
//
#include <hip/hip_runtime.h>

// CrossNet fused R8 = R1 (champion, 45.9us) with ONE isolated change:
// stream-grouped epilogue stores (16 KB contiguous burst per output stream
// per block) instead of per-chunk interleaving of the three streams.
// R2 had this grouping confounded with nontemporal stores (nt = -54%);
// this isolates the grouping variable.
// History: R1 45.9 (best); R2 nt+grouped 70.7; R3 split 60.9 (L3 ~= HBM BW);
// R4 wave-row 53.9; R5 forced lb 97.5 (spills); R6 b-reread 50.9;
// R7 persistent 47.7.

constexpr int BLK = 256;

typedef float f32x4 __attribute__((ext_vector_type(4)));

__device__ __forceinline__ float dot4(f32x4 a, f32x4 b) {
    return a.x * b.x + a.y * b.y + a.z * b.z + a.w * b.w;
}

__global__ __launch_bounds__(BLK) void crossnet_fused(
    const float* __restrict__ x,
    const float* __restrict__ w,
    const float* __restrict__ b,
    float* __restrict__ out,
    int B, int N)
{
    const int row = blockIdx.x;
    const int tid = threadIdx.x;

    const size_t base = (size_t)row * N;
    const f32x4* x4 = (const f32x4*)(x + base);
    const f32x4* w0 = (const f32x4*)(w);
    const f32x4* w1 = (const f32x4*)(w + N);
    const f32x4* w2 = (const f32x4*)(w + 2 * (size_t)N);
    const f32x4* b0 = (const f32x4*)(b);
    const f32x4* b1 = (const f32x4*)(b + N);
    const f32x4* b2 = (const f32x4*)(b + 2 * (size_t)N);

    f32x4 xv[4];
    f32x4 cb1v[4];  // b0
    f32x4 cb2v[4];  // b0+b1
    f32x4 cb3v[4];  // b0+b1+b2

    float p0 = 0.f, p1 = 0.f, p2 = 0.f;  // x . w0/w1/w2
    float q1 = 0.f, q2 = 0.f;            // b0 . w1, (b0+b1) . w2

    #pragma unroll
    for (int c = 0; c < 4; ++c) {
        const int idx = c * BLK + tid;
        const f32x4 xx = x4[idx];
        const f32x4 wa = w0[idx];
        const f32x4 wb = w1[idx];
        const f32x4 wc = w2[idx];
        const f32x4 ba = b0[idx];
        const f32x4 bb = b1[idx];
        const f32x4 bc = b2[idx];

        xv[c] = xx;
        const f32x4 c1v = ba;
        const f32x4 c2v = ba + bb;
        const f32x4 c3v = c2v + bc;
        cb1v[c] = c1v; cb2v[c] = c2v; cb3v[c] = c3v;

        p0 += dot4(xx, wa);
        p1 += dot4(xx, wb);
        p2 += dot4(xx, wc);
        q1 += dot4(c1v, wb);
        q2 += dot4(c2v, wc);
    }

    #pragma unroll
    for (int off = 32; off > 0; off >>= 1) {
        p0 += __shfl_down(p0, off);
        p1 += __shfl_down(p1, off);
        p2 += __shfl_down(p2, off);
        q1 += __shfl_down(q1, off);
        q2 += __shfl_down(q2, off);
    }

    __shared__ float red[4][8];
    const int wave = tid >> 6;
    const int lane = tid & 63;
    if (lane == 0) {
        red[wave][0] = p0; red[wave][1] = p1; red[wave][2] = p2;
        red[wave][3] = q1; red[wave][4] = q2;
    }
    __syncthreads();

    const float u0 = red[0][0] + red[1][0] + red[2][0] + red[3][0];
    const float u1 = red[0][1] + red[1][1] + red[2][1] + red[3][1];
    const float u2 = red[0][2] + red[1][2] + red[2][2] + red[3][2];
    const float t1 = red[0][3] + red[1][3] + red[2][3] + red[3][3];
    const float t2 = red[0][4] + red[1][4] + red[2][4] + red[3][4];

    const float c1 = 1.0f + u0;          // x1 = x*c1 + b0
    const float s1 = c1 * u1 + t1;
    const float c2 = c1 + s1;            // x2 = x*c2 + b0+b1
    const float s2 = c2 * u2 + t2;
    const float c3 = c2 + s2;            // x3 = x*c3 + b0+b1+b2

    f32x4* o0 = (f32x4*)(out + base);
    f32x4* o1 = (f32x4*)(out + (size_t)B * N + base);
    f32x4* o2 = (f32x4*)(out + 2 * (size_t)B * N + base);

    // Stream-grouped stores: 16 KB contiguous burst per stream per block.
    #pragma unroll
    for (int c = 0; c < 4; ++c) {
        const int idx = c * BLK + tid;
        o0[idx] = xv[c] * c1 + cb1v[c];
    }
    #pragma unroll
    for (int c = 0; c < 4; ++c) {
        const int idx = c * BLK + tid;
        o1[idx] = xv[c] * c2 + cb2v[c];
    }
    #pragma unroll
    for (int c = 0; c < 4; ++c) {
        const int idx = c * BLK + tid;
        o2[idx] = xv[c] * c3 + cb3v[c];
    }
}

extern "C" void kernel_launch(void* const* d_in, const int* in_sizes, int n_in,
                              void* d_out, int out_size, void* d_ws, size_t ws_size,
                              hipStream_t stream) {
    const float* x = (const float*)d_in[0];
    const float* w = (const float*)d_in[1];
    const float* b = (const float*)d_in[2];
    float* out = (float*)d_out;

    const int N = in_sizes[1] / 3;   // w is [3, N, 1]
    const int B = in_sizes[0] / N;   // x is [B, N]

    crossnet_fused<<<B, BLK, 0, stream>>>(x, w, b, out, B, N);
}